// Round 9
// baseline (106.170 us; speedup 1.0000x reference)
//
#include <hip/hip_runtime.h>
#include <math.h>

#define L_TOTAL 49152
#define NBLK 768
#define ROWS_PER_BLK 64
#define NCHUNK 32          // 1024 f / 32 f per chunk (32 f = 128 B = 1 line/row)

__device__ __forceinline__ float4 f4add(float4 a, float4 b) {
  return make_float4(a.x + b.x, a.y + b.y, a.z + b.z, a.w + b.w);
}

// Emulate np.float32 -> float16 (RNE, incl. subnormals) -> float32.
// Input x is positive and finite (x = 1/(l+1) <= 1).
__device__ __forceinline__ float fp16_roundtrip_pos(float x) {
  unsigned u = __float_as_uint(x);
  int e = (int)((u >> 23) & 0xffu) - 127;
  unsigned m = (u & 0x7fffffu) | 0x800000u;          // 24-bit mantissa
  int shift = (e >= -14) ? 13 : (13 + (-14 - e));    // extra shift for subnormals
  if (shift >= 25) return 0.0f;                      // underflow
  unsigned keep = m >> shift;
  unsigned rem = m & ((1u << shift) - 1u);
  unsigned halfbit = 1u << (shift - 1);
  if (rem > halfbit || (rem == halfbit && (keep & 1u))) keep++;
  return ldexpf((float)keep, e + shift - 23);
}

// Single fused kernel (row-per-lane, R8 pipeline) + flat aggregate scatter/
// gather across blocks:
//  - phase 1: block-scanned g in registers (identical to R8's gpart loop);
//  - publish: tid 255 stores the block total (8 floats) with agent-scope
//    atomics, then sets flags[bid] with a release store;
//  - gather: wave 0 polls flags[j] for j < bid (64-wide; all 768 blocks are
//    co-resident at 3 blocks/CU so predecessors always make progress; no
//    lookback chain -- aggregates don't depend on other blocks), sums
//    aggregates, butterfly-reduces, -> LDS;
//  - epilogue: v = a + offset, * fp16(1/(row+1)), + b_final, store out.
// flags are zeroed per call by a hipMemsetAsync node (poison-safety).
__global__ __launch_bounds__(256, 3) void fused_kernel(
    const int* __restrict__ ex, const float4* __restrict__ win4,
    const float4* __restrict__ pos4, const float4* __restrict__ wf4,
    const float* __restrict__ bfin, float4* __restrict__ out4,
    float* __restrict__ aggf, int* __restrict__ flags) {
  __shared__ float4 tile[2][ROWS_PER_BLK][9];   // 8 data float4 + 1 pad
  __shared__ float4 wtot[2][4];
  __shared__ float4 boffs[2];

  const int tid = threadIdx.x;
  const int lane = tid & 63;
  const int wv = tid >> 6;
  const int bid = blockIdx.x;
  const int rowBase = bid * ROWS_PER_BLK;

  const int r_st = tid >> 2;        // staging row 0..63
  const int q_st = tid & 3;         // staging float4-slot 0..3

  const int seg = lane >> 4;        // 0..3 f-segment
  const int r16 = lane & 15;        // row within wave
  const int myrow = wv * 16 + r16;  // block-local row
  const int grow = rowBase + myrow; // global row

  const float s0 = (float)ex[grow] - 3.0f;            // ((e/4*2-1)*2-1)==e-3
  const float s1 = (float)ex[L_TOTAL + grow] - 3.0f;

  float4 a0 = make_float4(0.f, 0.f, 0.f, 0.f);
  float4 a1 = make_float4(0.f, 0.f, 0.f, 0.f);

  const size_t prow = (size_t)(rowBase + r_st) * 256;  // pos4 row base

  // prologue: chunk 0 straight to LDS; chunk 1 into staging regs
  tile[0][r_st][q_st]     = pos4[prow + q_st];
  tile[0][r_st][q_st + 4] = pos4[prow + q_st + 4];
  float4 stA = pos4[prow + 8 + q_st];
  float4 stB = pos4[prow + 8 + q_st + 4];
  __syncthreads();

  for (int c = 0; c < NCHUNK; ++c) {
    // (1) ds_write chunk c+1 from regs (its loads are a full phase old)
    if (c + 1 < NCHUNK) {
      tile[(c + 1) & 1][r_st][q_st]     = stA;
      tile[(c + 1) & 1][r_st][q_st + 4] = stB;
    }
    // (2) issue global loads for chunk c+2 (stay in flight through barrier)
    if (c + 2 < NCHUNK) {
      const int f4n = (c + 2) * 8;
      stA = pos4[prow + f4n + q_st];
      stB = pos4[prow + f4n + q_st + 4];
    }
    // (3) compute chunk c: this lane's 8 f-values of its row
    const int f4b = c * 8 + seg * 2;
    const float4 p0 = tile[c & 1][myrow][seg * 2];
    const float4 p1 = tile[c & 1][myrow][seg * 2 + 1];
    const float4 w0 = win4[f4b];
    const float4 w1 = win4[f4b + 1];
    const float pe[8] = {p0.x, p0.y, p0.z, p0.w, p1.x, p1.y, p1.z, p1.w};
    const float we[8] = {w0.x, w0.y, w0.z, w0.w, w1.x, w1.y, w1.z, w1.w};
#pragma unroll
    for (int e = 0; e < 8; ++e) {
      const float4 wf = wf4[f4b * 4 + e];            // L1-broadcast
      const float t0 = fmaxf(fmaf(s0, we[e], pe[e]), 0.0f);
      const float t1 = fmaxf(fmaf(s1, we[e], pe[e]), 0.0f);
      a0.x = fmaf(t0, wf.x, a0.x); a0.y = fmaf(t0, wf.y, a0.y);
      a0.z = fmaf(t0, wf.z, a0.z); a0.w = fmaf(t0, wf.w, a0.w);
      a1.x = fmaf(t1, wf.x, a1.x); a1.y = fmaf(t1, wf.y, a1.y);
      a1.z = fmaf(t1, wf.z, a1.z); a1.w = fmaf(t1, wf.w, a1.w);
    }
    // (4) barrier: waits on ds_writes (lgkm), not on the c+2 global loads
    __syncthreads();
  }

  // cross-seg reduction (segments live 16 lanes apart): masks 16, 32
#define REDUCE8(MASK)                                                   \
  a0.x += __shfl_xor(a0.x, MASK); a0.y += __shfl_xor(a0.y, MASK);       \
  a0.z += __shfl_xor(a0.z, MASK); a0.w += __shfl_xor(a0.w, MASK);       \
  a1.x += __shfl_xor(a1.x, MASK); a1.y += __shfl_xor(a1.y, MASK);       \
  a1.z += __shfl_xor(a1.z, MASK); a1.w += __shfl_xor(a1.w, MASK);
  REDUCE8(16)
  REDUCE8(32)
#undef REDUCE8

  // inclusive scan over the 16 rows of this wave (value replicated per seg)
#pragma unroll
  for (int d = 1; d < 16; d <<= 1) {
    const float u0 = __shfl_up(a0.x, d), u1 = __shfl_up(a0.y, d);
    const float u2 = __shfl_up(a0.z, d), u3 = __shfl_up(a0.w, d);
    const float u4 = __shfl_up(a1.x, d), u5 = __shfl_up(a1.y, d);
    const float u6 = __shfl_up(a1.z, d), u7 = __shfl_up(a1.w, d);
    if (r16 >= d) {
      a0.x += u0; a0.y += u1; a0.z += u2; a0.w += u3;
      a1.x += u4; a1.y += u5; a1.z += u6; a1.w += u7;
    }
  }

  // wave totals (value at r16==15) -> LDS for cross-wave offsets
  float4 t0, t1;
  t0.x = __shfl(a0.x, 15); t0.y = __shfl(a0.y, 15);
  t0.z = __shfl(a0.z, 15); t0.w = __shfl(a0.w, 15);
  t1.x = __shfl(a1.x, 15); t1.y = __shfl(a1.y, 15);
  t1.z = __shfl(a1.z, 15); t1.w = __shfl(a1.w, 15);
  if (lane == 0) { wtot[0][wv] = t0; wtot[1][wv] = t1; }
  __syncthreads();
  float4 o0 = make_float4(0.f, 0.f, 0.f, 0.f);
  float4 o1 = make_float4(0.f, 0.f, 0.f, 0.f);
  for (int j = 0; j < wv; ++j) {
    o0 = f4add(o0, wtot[0][j]);
    o1 = f4add(o1, wtot[1][j]);
  }
  a0 = f4add(a0, o0);
  a1 = f4add(a1, o1);

  // publish block aggregate (tid 255 = wv 3, r16 15 -> block-inclusive total)
  if (tid == 255) {
    const float v[8] = {a0.x, a0.y, a0.z, a0.w, a1.x, a1.y, a1.z, a1.w};
#pragma unroll
    for (int k = 0; k < 8; ++k)
      __hip_atomic_store(&aggf[(size_t)bid * 8 + k], v[k], __ATOMIC_RELAXED,
                         __HIP_MEMORY_SCOPE_AGENT);
    __hip_atomic_store(&flags[bid], 1, __ATOMIC_RELEASE,
                       __HIP_MEMORY_SCOPE_AGENT);
  }

  // gather preceding blocks' aggregates (wave 0; 64-wide; flat, no chain)
  if (wv == 0) {
    float4 q0 = make_float4(0.f, 0.f, 0.f, 0.f);
    float4 q1 = make_float4(0.f, 0.f, 0.f, 0.f);
    for (int base = 0; base < bid; base += 64) {
      const int j = base + lane;
      if (j < bid) {
        while (__hip_atomic_load(&flags[j], __ATOMIC_ACQUIRE,
                                 __HIP_MEMORY_SCOPE_AGENT) == 0) {
          __builtin_amdgcn_s_sleep(1);
        }
        const float* aj = &aggf[(size_t)j * 8];
        q0.x += __hip_atomic_load(aj + 0, __ATOMIC_RELAXED, __HIP_MEMORY_SCOPE_AGENT);
        q0.y += __hip_atomic_load(aj + 1, __ATOMIC_RELAXED, __HIP_MEMORY_SCOPE_AGENT);
        q0.z += __hip_atomic_load(aj + 2, __ATOMIC_RELAXED, __HIP_MEMORY_SCOPE_AGENT);
        q0.w += __hip_atomic_load(aj + 3, __ATOMIC_RELAXED, __HIP_MEMORY_SCOPE_AGENT);
        q1.x += __hip_atomic_load(aj + 4, __ATOMIC_RELAXED, __HIP_MEMORY_SCOPE_AGENT);
        q1.y += __hip_atomic_load(aj + 5, __ATOMIC_RELAXED, __HIP_MEMORY_SCOPE_AGENT);
        q1.z += __hip_atomic_load(aj + 6, __ATOMIC_RELAXED, __HIP_MEMORY_SCOPE_AGENT);
        q1.w += __hip_atomic_load(aj + 7, __ATOMIC_RELAXED, __HIP_MEMORY_SCOPE_AGENT);
      }
    }
#pragma unroll
    for (int off = 32; off > 0; off >>= 1) {
      q0.x += __shfl_xor(q0.x, off); q0.y += __shfl_xor(q0.y, off);
      q0.z += __shfl_xor(q0.z, off); q0.w += __shfl_xor(q0.w, off);
      q1.x += __shfl_xor(q1.x, off); q1.y += __shfl_xor(q1.y, off);
      q1.z += __shfl_xor(q1.z, off); q1.w += __shfl_xor(q1.w, off);
    }
    if (lane == 0) { boffs[0] = q0; boffs[1] = q1; }
  }
  __syncthreads();

  // epilogue: add cross-block offset, scale by fp16(1/(row+1)), +b_final
  if (seg == 0) {
    const float4 v0 = f4add(a0, boffs[0]);
    const float4 v1 = f4add(a1, boffs[1]);
    const float factor = fp16_roundtrip_pos(1.0f / (float)(grow + 1));
    float4 u0, u1;
    u0.x = fmaf(v0.x, factor, bfin[0]);
    u0.y = fmaf(v0.y, factor, bfin[1]);
    u0.z = fmaf(v0.z, factor, bfin[2]);
    u0.w = fmaf(v0.w, factor, bfin[3]);
    u1.x = fmaf(v1.x, factor, bfin[0]);
    u1.y = fmaf(v1.y, factor, bfin[1]);
    u1.z = fmaf(v1.z, factor, bfin[2]);
    u1.w = fmaf(v1.w, factor, bfin[3]);
    out4[grow] = u0;
    out4[L_TOTAL + grow] = u1;
  }
}

extern "C" void kernel_launch(void* const* d_in, const int* in_sizes, int n_in,
                              void* d_out, int out_size, void* d_ws, size_t ws_size,
                              hipStream_t stream) {
  const int* ex = (const int*)d_in[0];            // example [2,128,128,3] int32
  const float4* win4 = (const float4*)d_in[1];    // W_in [1,1024]
  const float4* pos4 = (const float4*)d_in[2];    // pos_enc [49152,1024]
  const float4* wf4 = (const float4*)d_in[3];     // W_final [1024,4]
  const float* bfin = (const float*)d_in[4];      // b_final [4]
  float4* out4 = (float4*)d_out;

  float* aggf = (float*)d_ws;                     // [NBLK][8] floats (24 KB)
  int* flags = (int*)(aggf + (size_t)NBLK * 8);   // [NBLK] ints (3 KB)

  hipMemsetAsync(flags, 0, NBLK * sizeof(int), stream);
  fused_kernel<<<NBLK, 256, 0, stream>>>(ex, win4, pos4, wf4, bfin, out4,
                                         aggf, flags);
}

// Round 10
// 92.759 us; speedup vs baseline: 1.1446x; 1.1446x over previous
//
#include <hip/hip_runtime.h>
#include <math.h>

#define L_TOTAL 49152
#define NBLK 768
#define ROWS_PER_BLK 64
#define NCHUNK 16          // 1024 f / 64 f per chunk (64 f = 256 B per row)

__device__ __forceinline__ float4 f4add(float4 a, float4 b) {
  return make_float4(a.x + b.x, a.y + b.y, a.z + b.z, a.w + b.w);
}

// Emulate np.float32 -> float16 (RNE, incl. subnormals) -> float32.
// Input x is positive and finite (x = 1/(l+1) <= 1).
__device__ __forceinline__ float fp16_roundtrip_pos(float x) {
  unsigned u = __float_as_uint(x);
  int e = (int)((u >> 23) & 0xffu) - 127;
  unsigned m = (u & 0x7fffffu) | 0x800000u;          // 24-bit mantissa
  int shift = (e >= -14) ? 13 : (13 + (-14 - e));    // extra shift for subnormals
  if (shift >= 25) return 0.0f;                      // underflow
  unsigned keep = m >> shift;
  unsigned rem = m & ((1u << shift) - 1u);
  unsigned halfbit = 1u << (shift - 1);
  if (rem > halfbit || (rem == halfbit && (keep & 1u))) keep++;
  return ldexpf((float)keep, e + shift - 23);
}

// Kernel A (row-per-lane, 2-deep staged pipeline, 64-float chunks):
// iter c: ds_write chunk c+1 (regs, loaded one full phase ago) -> buf[(c+1)&1];
//         issue global loads chunk c+2 -> regs (in flight across barriers);
//         compute chunk c from buf[c&1]; barrier.
// 16 chunks -> 16 barriers (half of R8), 64 B/thread staged in regs.
__global__ __launch_bounds__(256, 3) void gpart_kernel(
    const int* __restrict__ ex, const float4* __restrict__ win4,
    const float4* __restrict__ pos4, const float4* __restrict__ wf4,
    float4* __restrict__ gbuf, float4* __restrict__ pp) {
  __shared__ float4 tile[2][ROWS_PER_BLK][17];   // 16 data float4 + 1 pad
  __shared__ float4 wtot[2][4];

  const int tid = threadIdx.x;
  const int lane = tid & 63;
  const int wv = tid >> 6;
  const int rowBase = blockIdx.x * ROWS_PER_BLK;

  const int r_st = tid >> 2;        // staging row 0..63
  const int q_st = tid & 3;         // staging base slot 0..3 (cols q+4j)

  const int seg = lane >> 4;        // 0..3 f-segment (16 floats each/chunk)
  const int r16 = lane & 15;        // row within wave
  const int myrow = wv * 16 + r16;  // block-local row
  const int grow = rowBase + myrow; // global row

  const float s0 = (float)ex[grow] - 3.0f;            // ((e/4*2-1)*2-1)==e-3
  const float s1 = (float)ex[L_TOTAL + grow] - 3.0f;

  float4 a0 = make_float4(0.f, 0.f, 0.f, 0.f);
  float4 a1 = make_float4(0.f, 0.f, 0.f, 0.f);

  const size_t prow = (size_t)(rowBase + r_st) * 256;  // pos4 row base

  // prologue: chunk 0 straight to LDS; chunk 1 into staging regs
  float4 st[4];
#pragma unroll
  for (int j = 0; j < 4; ++j)
    tile[0][r_st][q_st + 4 * j] = pos4[prow + q_st + 4 * j];
#pragma unroll
  for (int j = 0; j < 4; ++j)
    st[j] = pos4[prow + 16 + q_st + 4 * j];
  __syncthreads();

  for (int c = 0; c < NCHUNK; ++c) {
    // (1) ds_write chunk c+1 from regs (its loads are a full phase old)
    if (c + 1 < NCHUNK) {
#pragma unroll
      for (int j = 0; j < 4; ++j)
        tile[(c + 1) & 1][r_st][q_st + 4 * j] = st[j];
    }
    // (2) issue global loads for chunk c+2 (stay in flight through barrier)
    if (c + 2 < NCHUNK) {
      const int f4n = (c + 2) * 16;
#pragma unroll
      for (int j = 0; j < 4; ++j)
        st[j] = pos4[prow + f4n + q_st + 4 * j];
    }
    // (3) compute chunk c: this lane's 16 f-values of its row
    const int f4b = c * 16 + seg * 4;
#pragma unroll
    for (int j = 0; j < 4; ++j) {
      const float4 p = tile[c & 1][myrow][seg * 4 + j];
      const float4 w = win4[f4b + j];
      const float pe[4] = {p.x, p.y, p.z, p.w};
      const float we[4] = {w.x, w.y, w.z, w.w};
#pragma unroll
      for (int k = 0; k < 4; ++k) {
        const float4 wf = wf4[(f4b + j) * 4 + k];     // L1-broadcast
        const float t0 = fmaxf(fmaf(s0, we[k], pe[k]), 0.0f);
        const float t1 = fmaxf(fmaf(s1, we[k], pe[k]), 0.0f);
        a0.x = fmaf(t0, wf.x, a0.x); a0.y = fmaf(t0, wf.y, a0.y);
        a0.z = fmaf(t0, wf.z, a0.z); a0.w = fmaf(t0, wf.w, a0.w);
        a1.x = fmaf(t1, wf.x, a1.x); a1.y = fmaf(t1, wf.y, a1.y);
        a1.z = fmaf(t1, wf.z, a1.z); a1.w = fmaf(t1, wf.w, a1.w);
      }
    }
    // (4) barrier: waits on ds_writes (lgkm), not on the c+2 global loads
    __syncthreads();
  }

  // cross-seg reduction (segments live 16 lanes apart): masks 16, 32
#define REDUCE8(MASK)                                                   \
  a0.x += __shfl_xor(a0.x, MASK); a0.y += __shfl_xor(a0.y, MASK);       \
  a0.z += __shfl_xor(a0.z, MASK); a0.w += __shfl_xor(a0.w, MASK);       \
  a1.x += __shfl_xor(a1.x, MASK); a1.y += __shfl_xor(a1.y, MASK);       \
  a1.z += __shfl_xor(a1.z, MASK); a1.w += __shfl_xor(a1.w, MASK);
  REDUCE8(16)
  REDUCE8(32)
#undef REDUCE8

  // inclusive scan over the 16 rows of this wave (value replicated per seg)
#pragma unroll
  for (int d = 1; d < 16; d <<= 1) {
    const float u0 = __shfl_up(a0.x, d), u1 = __shfl_up(a0.y, d);
    const float u2 = __shfl_up(a0.z, d), u3 = __shfl_up(a0.w, d);
    const float u4 = __shfl_up(a1.x, d), u5 = __shfl_up(a1.y, d);
    const float u6 = __shfl_up(a1.z, d), u7 = __shfl_up(a1.w, d);
    if (r16 >= d) {
      a0.x += u0; a0.y += u1; a0.z += u2; a0.w += u3;
      a1.x += u4; a1.y += u5; a1.z += u6; a1.w += u7;
    }
  }

  // wave totals (value at r16==15) -> LDS for cross-wave offsets
  float4 t0, t1;
  t0.x = __shfl(a0.x, 15); t0.y = __shfl(a0.y, 15);
  t0.z = __shfl(a0.z, 15); t0.w = __shfl(a0.w, 15);
  t1.x = __shfl(a1.x, 15); t1.y = __shfl(a1.y, 15);
  t1.z = __shfl(a1.z, 15); t1.w = __shfl(a1.w, 15);
  if (lane == 0) { wtot[0][wv] = t0; wtot[1][wv] = t1; }
  __syncthreads();
  float4 o0 = make_float4(0.f, 0.f, 0.f, 0.f);
  float4 o1 = make_float4(0.f, 0.f, 0.f, 0.f);
  for (int j = 0; j < wv; ++j) {
    o0 = f4add(o0, wtot[0][j]);
    o1 = f4add(o1, wtot[1][j]);
  }
  a0 = f4add(a0, o0);
  a1 = f4add(a1, o1);

  if (seg == 0) {           // one copy per row writes block-scanned g
    gbuf[grow] = a0;
    gbuf[L_TOTAL + grow] = a1;
  }
  if (tid == 255) {         // wv=3, r16=15 -> block-inclusive total
    pp[blockIdx.x] = a0;
    pp[NBLK + blockIdx.x] = a1;
  }
}

// Kernel B: out[b,row] = (g_scanned[b,row] + sum of preceding blocks' totals)
//           * fp16(1/(row+1)) + b_final. pp is L2-hot (24 KB).
__global__ __launch_bounds__(128, 8) void finish_kernel(
    const float4* __restrict__ gbuf, const float4* __restrict__ pp,
    const float* __restrict__ bfin, float4* __restrict__ out4) {
  const int tid = threadIdx.x;
  const int bb = tid >> 6;   // batch 0/1
  const int i = tid & 63;    // row within block
  const int bid = blockIdx.x;

  // offset = sum of pp[bb][j] for j < bid (wave-strided + butterfly)
  float4 q = make_float4(0.f, 0.f, 0.f, 0.f);
  for (int j = i; j < bid; j += 64) q = f4add(q, pp[bb * NBLK + j]);
#pragma unroll
  for (int off = 32; off > 0; off >>= 1) {
    q.x += __shfl_xor(q.x, off); q.y += __shfl_xor(q.y, off);
    q.z += __shfl_xor(q.z, off); q.w += __shfl_xor(q.w, off);
  }

  const int row = bid * ROWS_PER_BLK + i;
  const float4 v = f4add(gbuf[(size_t)bb * L_TOTAL + row], q);
  const float factor = fp16_roundtrip_pos(1.0f / (float)(row + 1));
  float4 o;
  o.x = fmaf(v.x, factor, bfin[0]);
  o.y = fmaf(v.y, factor, bfin[1]);
  o.z = fmaf(v.z, factor, bfin[2]);
  o.w = fmaf(v.w, factor, bfin[3]);
  out4[(size_t)bb * L_TOTAL + row] = o;
}

extern "C" void kernel_launch(void* const* d_in, const int* in_sizes, int n_in,
                              void* d_out, int out_size, void* d_ws, size_t ws_size,
                              hipStream_t stream) {
  const int* ex = (const int*)d_in[0];            // example [2,128,128,3] int32
  const float4* win4 = (const float4*)d_in[1];    // W_in [1,1024]
  const float4* pos4 = (const float4*)d_in[2];    // pos_enc [49152,1024]
  const float4* wf4 = (const float4*)d_in[3];     // W_final [1024,4]
  const float* bfin = (const float*)d_in[4];      // b_final [4]
  float4* out4 = (float4*)d_out;

  float4* gbuf = (float4*)d_ws;                   // [2][L_TOTAL] float4
  float4* pp = gbuf + (size_t)2 * L_TOTAL;        // [2][NBLK] float4

  gpart_kernel<<<NBLK, 256, 0, stream>>>(ex, win4, pos4, wf4, gbuf, pp);
  finish_kernel<<<NBLK, 128, 0, stream>>>(gbuf, pp, bfin, out4);
}

// Round 11
// 51.788 us; speedup vs baseline: 2.0501x; 1.7911x over previous
//
#include <hip/hip_runtime.h>
#include <math.h>

#define L_TOTAL 49152
#define NBLK 1536
#define ROWS_PER_BLK 32    // 1536 blocks = 6 blocks/CU = 24 waves/CU
#define NCHUNK 32          // 1024 f / 32 f per chunk (32 f = 128 B per row)

__device__ __forceinline__ float4 f4add(float4 a, float4 b) {
  return make_float4(a.x + b.x, a.y + b.y, a.z + b.z, a.w + b.w);
}

// Emulate np.float32 -> float16 (RNE, incl. subnormals) -> float32.
// Input x is positive and finite (x = 1/(l+1) <= 1).
__device__ __forceinline__ float fp16_roundtrip_pos(float x) {
  unsigned u = __float_as_uint(x);
  int e = (int)((u >> 23) & 0xffu) - 127;
  unsigned m = (u & 0x7fffffu) | 0x800000u;          // 24-bit mantissa
  int shift = (e >= -14) ? 13 : (13 + (-14 - e));    // extra shift for subnormals
  if (shift >= 25) return 0.0f;                      // underflow
  unsigned keep = m >> shift;
  unsigned rem = m & ((1u << shift) - 1u);
  unsigned halfbit = 1u << (shift - 1);
  if (rem > halfbit || (rem == halfbit && (keep & 1u))) keep++;
  return ldexpf((float)keep, e + shift - 23);
}

// Kernel A (row-per-lane, 2-deep staged pipeline -- R8 structure at 2x
// occupancy): 32 rows/block, 4 waves; wave = 8 rows x 8 f-segments.
// iter c: ds_write chunk c+1 (regs, loaded one full phase ago);
//         issue global loads chunk c+2 -> regs (in flight across barrier);
//         compute chunk c; barrier.
__global__ __launch_bounds__(256, 6) void gpart_kernel(
    const int* __restrict__ ex, const float4* __restrict__ win4,
    const float4* __restrict__ pos4, const float4* __restrict__ wf4,
    float4* __restrict__ gbuf, float4* __restrict__ pp) {
  __shared__ float4 tile[2][ROWS_PER_BLK][9];   // 8 data float4 + 1 pad
  __shared__ float4 wtot[2][4];

  const int tid = threadIdx.x;
  const int lane = tid & 63;
  const int wv = tid >> 6;
  const int rowBase = blockIdx.x * ROWS_PER_BLK;

  const int r_st = tid >> 3;        // staging row 0..31
  const int q_st = tid & 7;         // staging float4-slot 0..7

  const int seg = lane >> 3;        // 0..7 f-segment (4 floats per chunk)
  const int r8 = lane & 7;          // row within wave
  const int myrow = wv * 8 + r8;    // block-local row
  const int grow = rowBase + myrow; // global row

  const float s0 = (float)ex[grow] - 3.0f;            // ((e/4*2-1)*2-1)==e-3
  const float s1 = (float)ex[L_TOTAL + grow] - 3.0f;

  float4 a0 = make_float4(0.f, 0.f, 0.f, 0.f);
  float4 a1 = make_float4(0.f, 0.f, 0.f, 0.f);

  const size_t prow = (size_t)(rowBase + r_st) * 256;  // pos4 row base

  // prologue: chunk 0 straight to LDS; chunk 1 into the staging reg
  tile[0][r_st][q_st] = pos4[prow + q_st];
  float4 st = pos4[prow + 8 + q_st];
  __syncthreads();

  for (int c = 0; c < NCHUNK; ++c) {
    // (1) ds_write chunk c+1 from the reg (its load is a full phase old)
    if (c + 1 < NCHUNK) tile[(c + 1) & 1][r_st][q_st] = st;
    // (2) issue global load for chunk c+2 (stays in flight through barrier)
    if (c + 2 < NCHUNK) st = pos4[prow + (size_t)(c + 2) * 8 + q_st];
    // (3) compute chunk c: this lane's 4 f-values of its row
    const int f4i = c * 8 + seg;
    const float4 p = tile[c & 1][myrow][seg];
    const float4 w = win4[f4i];
    const float pe[4] = {p.x, p.y, p.z, p.w};
    const float we[4] = {w.x, w.y, w.z, w.w};
#pragma unroll
    for (int k = 0; k < 4; ++k) {
      const float4 wf = wf4[f4i * 4 + k];              // L1-broadcast
      const float t0 = fmaxf(fmaf(s0, we[k], pe[k]), 0.0f);
      const float t1 = fmaxf(fmaf(s1, we[k], pe[k]), 0.0f);
      a0.x = fmaf(t0, wf.x, a0.x); a0.y = fmaf(t0, wf.y, a0.y);
      a0.z = fmaf(t0, wf.z, a0.z); a0.w = fmaf(t0, wf.w, a0.w);
      a1.x = fmaf(t1, wf.x, a1.x); a1.y = fmaf(t1, wf.y, a1.y);
      a1.z = fmaf(t1, wf.z, a1.z); a1.w = fmaf(t1, wf.w, a1.w);
    }
    // (4) barrier: waits on ds_writes (lgkm), not on the c+2 global load
    __syncthreads();
  }

  // cross-seg reduction (segments live 8 lanes apart): masks 8, 16, 32
#define REDUCE8(MASK)                                                   \
  a0.x += __shfl_xor(a0.x, MASK); a0.y += __shfl_xor(a0.y, MASK);       \
  a0.z += __shfl_xor(a0.z, MASK); a0.w += __shfl_xor(a0.w, MASK);       \
  a1.x += __shfl_xor(a1.x, MASK); a1.y += __shfl_xor(a1.y, MASK);       \
  a1.z += __shfl_xor(a1.z, MASK); a1.w += __shfl_xor(a1.w, MASK);
  REDUCE8(8)
  REDUCE8(16)
  REDUCE8(32)
#undef REDUCE8

  // inclusive scan over the 8 rows of this wave (value replicated per seg)
#pragma unroll
  for (int d = 1; d < 8; d <<= 1) {
    const float u0 = __shfl_up(a0.x, d), u1 = __shfl_up(a0.y, d);
    const float u2 = __shfl_up(a0.z, d), u3 = __shfl_up(a0.w, d);
    const float u4 = __shfl_up(a1.x, d), u5 = __shfl_up(a1.y, d);
    const float u6 = __shfl_up(a1.z, d), u7 = __shfl_up(a1.w, d);
    if (r8 >= d) {
      a0.x += u0; a0.y += u1; a0.z += u2; a0.w += u3;
      a1.x += u4; a1.y += u5; a1.z += u6; a1.w += u7;
    }
  }

  // wave totals (row 7 value, lane 7) -> LDS for cross-wave offsets
  float4 t0, t1;
  t0.x = __shfl(a0.x, 7); t0.y = __shfl(a0.y, 7);
  t0.z = __shfl(a0.z, 7); t0.w = __shfl(a0.w, 7);
  t1.x = __shfl(a1.x, 7); t1.y = __shfl(a1.y, 7);
  t1.z = __shfl(a1.z, 7); t1.w = __shfl(a1.w, 7);
  if (lane == 0) { wtot[0][wv] = t0; wtot[1][wv] = t1; }
  __syncthreads();
  float4 o0 = make_float4(0.f, 0.f, 0.f, 0.f);
  float4 o1 = make_float4(0.f, 0.f, 0.f, 0.f);
  for (int j = 0; j < wv; ++j) {
    o0 = f4add(o0, wtot[0][j]);
    o1 = f4add(o1, wtot[1][j]);
  }
  a0 = f4add(a0, o0);
  a1 = f4add(a1, o1);

  if (seg == 0) {           // one copy per row writes block-scanned g
    gbuf[grow] = a0;
    gbuf[L_TOTAL + grow] = a1;
  }
  if (tid == 255) {         // wv=3, r8=7 -> block-inclusive total
    pp[blockIdx.x] = a0;
    pp[NBLK + blockIdx.x] = a1;
  }
}

// Kernel B: out[b,row] = (g_scanned[b,row] + sum of preceding blocks' totals)
//           * fp16(1/(row+1)) + b_final. pp is L2-hot (48 KB).
__global__ __launch_bounds__(128, 8) void finish_kernel(
    const float4* __restrict__ gbuf, const float4* __restrict__ pp,
    const float* __restrict__ bfin, float4* __restrict__ out4) {
  const int tid = threadIdx.x;
  const int bb = tid >> 6;   // batch 0/1
  const int i = tid & 63;    // lane within the walk
  const int bid = blockIdx.x;

  // offset = sum of pp[bb][j] for j < bid (wave-strided + butterfly)
  float4 q = make_float4(0.f, 0.f, 0.f, 0.f);
  for (int j = i; j < bid; j += 64) q = f4add(q, pp[bb * NBLK + j]);
#pragma unroll
  for (int off = 32; off > 0; off >>= 1) {
    q.x += __shfl_xor(q.x, off); q.y += __shfl_xor(q.y, off);
    q.z += __shfl_xor(q.z, off); q.w += __shfl_xor(q.w, off);
  }

  if (i < ROWS_PER_BLK) {
    const int row = bid * ROWS_PER_BLK + i;
    const float4 v = f4add(gbuf[(size_t)bb * L_TOTAL + row], q);
    const float factor = fp16_roundtrip_pos(1.0f / (float)(row + 1));
    float4 o;
    o.x = fmaf(v.x, factor, bfin[0]);
    o.y = fmaf(v.y, factor, bfin[1]);
    o.z = fmaf(v.z, factor, bfin[2]);
    o.w = fmaf(v.w, factor, bfin[3]);
    out4[(size_t)bb * L_TOTAL + row] = o;
  }
}

extern "C" void kernel_launch(void* const* d_in, const int* in_sizes, int n_in,
                              void* d_out, int out_size, void* d_ws, size_t ws_size,
                              hipStream_t stream) {
  const int* ex = (const int*)d_in[0];            // example [2,128,128,3] int32
  const float4* win4 = (const float4*)d_in[1];    // W_in [1,1024]
  const float4* pos4 = (const float4*)d_in[2];    // pos_enc [49152,1024]
  const float4* wf4 = (const float4*)d_in[3];     // W_final [1024,4]
  const float* bfin = (const float*)d_in[4];      // b_final [4]
  float4* out4 = (float4*)d_out;

  float4* gbuf = (float4*)d_ws;                   // [2][L_TOTAL] float4
  float4* pp = gbuf + (size_t)2 * L_TOTAL;        // [2][NBLK] float4

  gpart_kernel<<<NBLK, 256, 0, stream>>>(ex, win4, pos4, wf4, gbuf, pp);
  finish_kernel<<<NBLK, 128, 0, stream>>>(gbuf, pp, bfin, out4);
}

// Round 12
// 48.274 us; speedup vs baseline: 2.1993x; 1.0728x over previous
//
#include <hip/hip_runtime.h>
#include <math.h>

#define L_TOTAL 49152
#define NBLK 768
#define ROWS_PER_BLK 64
#define NCHUNK 32          // 1024 f / 32 f per chunk (32 f = 128 B per row)

__device__ __forceinline__ float4 f4add(float4 a, float4 b) {
  return make_float4(a.x + b.x, a.y + b.y, a.z + b.z, a.w + b.w);
}

// Emulate np.float32 -> float16 (RNE, incl. subnormals) -> float32.
// Input x is positive and finite (x = 1/(l+1) <= 1).
__device__ __forceinline__ float fp16_roundtrip_pos(float x) {
  unsigned u = __float_as_uint(x);
  int e = (int)((u >> 23) & 0xffu) - 127;
  unsigned m = (u & 0x7fffffu) | 0x800000u;          // 24-bit mantissa
  int shift = (e >= -14) ? 13 : (13 + (-14 - e));    // extra shift for subnormals
  if (shift >= 25) return 0.0f;                      // underflow
  unsigned keep = m >> shift;
  unsigned rem = m & ((1u << shift) - 1u);
  unsigned halfbit = 1u << (shift - 1);
  if (rem > halfbit || (rem == halfbit && (keep & 1u))) keep++;
  return ldexpf((float)keep, e + shift - 23);
}

// Kernel A -- byte-identical to the R8 version (proven 48.0 us config).
// Row-per-lane, 2-deep staged pipeline, 32-float chunks, 3 blocks/CU.
__global__ __launch_bounds__(256, 3) void gpart_kernel(
    const int* __restrict__ ex, const float4* __restrict__ win4,
    const float4* __restrict__ pos4, const float4* __restrict__ wf4,
    float4* __restrict__ gbuf, float4* __restrict__ pp) {
  __shared__ float4 tile[2][ROWS_PER_BLK][9];   // 8 data float4 + 1 pad
  __shared__ float4 wtot[2][4];

  const int tid = threadIdx.x;
  const int lane = tid & 63;
  const int wv = tid >> 6;
  const int rowBase = blockIdx.x * ROWS_PER_BLK;

  const int r_st = tid >> 2;        // staging row 0..63
  const int q_st = tid & 3;         // staging float4-slot 0..3

  const int seg = lane >> 4;        // 0..3 f-segment
  const int r16 = lane & 15;        // row within wave
  const int myrow = wv * 16 + r16;  // block-local row
  const int grow = rowBase + myrow; // global row

  const float s0 = (float)ex[grow] - 3.0f;            // ((e/4*2-1)*2-1)==e-3
  const float s1 = (float)ex[L_TOTAL + grow] - 3.0f;

  float4 a0 = make_float4(0.f, 0.f, 0.f, 0.f);
  float4 a1 = make_float4(0.f, 0.f, 0.f, 0.f);

  const size_t prow = (size_t)(rowBase + r_st) * 256;  // pos4 row base

  // prologue: chunk 0 straight to LDS; chunk 1 into staging regs
  tile[0][r_st][q_st]     = pos4[prow + q_st];
  tile[0][r_st][q_st + 4] = pos4[prow + q_st + 4];
  float4 stA = pos4[prow + 8 + q_st];
  float4 stB = pos4[prow + 8 + q_st + 4];
  __syncthreads();

  for (int c = 0; c < NCHUNK; ++c) {
    // (1) ds_write chunk c+1 from regs (its loads are a full phase old)
    if (c + 1 < NCHUNK) {
      tile[(c + 1) & 1][r_st][q_st]     = stA;
      tile[(c + 1) & 1][r_st][q_st + 4] = stB;
    }
    // (2) issue global loads for chunk c+2 (stay in flight through barrier)
    if (c + 2 < NCHUNK) {
      const int f4n = (c + 2) * 8;
      stA = pos4[prow + f4n + q_st];
      stB = pos4[prow + f4n + q_st + 4];
    }
    // (3) compute chunk c: this lane's 8 f-values of its row
    const int f4b = c * 8 + seg * 2;
    const float4 p0 = tile[c & 1][myrow][seg * 2];
    const float4 p1 = tile[c & 1][myrow][seg * 2 + 1];
    const float4 w0 = win4[f4b];
    const float4 w1 = win4[f4b + 1];
    const float pe[8] = {p0.x, p0.y, p0.z, p0.w, p1.x, p1.y, p1.z, p1.w};
    const float we[8] = {w0.x, w0.y, w0.z, w0.w, w1.x, w1.y, w1.z, w1.w};
#pragma unroll
    for (int e = 0; e < 8; ++e) {
      const float4 wf = wf4[f4b * 4 + e];            // L1-broadcast
      const float t0 = fmaxf(fmaf(s0, we[e], pe[e]), 0.0f);
      const float t1 = fmaxf(fmaf(s1, we[e], pe[e]), 0.0f);
      a0.x = fmaf(t0, wf.x, a0.x); a0.y = fmaf(t0, wf.y, a0.y);
      a0.z = fmaf(t0, wf.z, a0.z); a0.w = fmaf(t0, wf.w, a0.w);
      a1.x = fmaf(t1, wf.x, a1.x); a1.y = fmaf(t1, wf.y, a1.y);
      a1.z = fmaf(t1, wf.z, a1.z); a1.w = fmaf(t1, wf.w, a1.w);
    }
    // (4) barrier: waits on ds_writes (lgkm), not on the c+2 global loads
    __syncthreads();
  }

  // cross-seg reduction (segments live 16 lanes apart): masks 16, 32
#define REDUCE8(MASK)                                                   \
  a0.x += __shfl_xor(a0.x, MASK); a0.y += __shfl_xor(a0.y, MASK);       \
  a0.z += __shfl_xor(a0.z, MASK); a0.w += __shfl_xor(a0.w, MASK);       \
  a1.x += __shfl_xor(a1.x, MASK); a1.y += __shfl_xor(a1.y, MASK);       \
  a1.z += __shfl_xor(a1.z, MASK); a1.w += __shfl_xor(a1.w, MASK);
  REDUCE8(16)
  REDUCE8(32)
#undef REDUCE8

  // inclusive scan over the 16 rows of this wave (value replicated per seg)
#pragma unroll
  for (int d = 1; d < 16; d <<= 1) {
    const float u0 = __shfl_up(a0.x, d), u1 = __shfl_up(a0.y, d);
    const float u2 = __shfl_up(a0.z, d), u3 = __shfl_up(a0.w, d);
    const float u4 = __shfl_up(a1.x, d), u5 = __shfl_up(a1.y, d);
    const float u6 = __shfl_up(a1.z, d), u7 = __shfl_up(a1.w, d);
    if (r16 >= d) {
      a0.x += u0; a0.y += u1; a0.z += u2; a0.w += u3;
      a1.x += u4; a1.y += u5; a1.z += u6; a1.w += u7;
    }
  }

  // wave totals (value at r16==15) -> LDS for cross-wave offsets
  float4 t0, t1;
  t0.x = __shfl(a0.x, 15); t0.y = __shfl(a0.y, 15);
  t0.z = __shfl(a0.z, 15); t0.w = __shfl(a0.w, 15);
  t1.x = __shfl(a1.x, 15); t1.y = __shfl(a1.y, 15);
  t1.z = __shfl(a1.z, 15); t1.w = __shfl(a1.w, 15);
  if (lane == 0) { wtot[0][wv] = t0; wtot[1][wv] = t1; }
  __syncthreads();
  float4 o0 = make_float4(0.f, 0.f, 0.f, 0.f);
  float4 o1 = make_float4(0.f, 0.f, 0.f, 0.f);
  for (int j = 0; j < wv; ++j) {
    o0 = f4add(o0, wtot[0][j]);
    o1 = f4add(o1, wtot[1][j]);
  }
  a0 = f4add(a0, o0);
  a1 = f4add(a1, o1);

  if (seg == 0) {           // one copy per row writes block-scanned g
    gbuf[grow] = a0;
    gbuf[L_TOTAL + grow] = a1;
  }
  if (tid == 255) {         // wv=3, r16=15 -> block-inclusive total
    pp[blockIdx.x] = a0;
    pp[NBLK + blockIdx.x] = a1;
  }
}

// Kernel B (slimmed): 384 blocks x 256 threads. Block k covers A-blocks
// {2k, 2k+1} = rows [128k, 128k+128) for BOTH batches (waves 0-1: batch 0,
// waves 2-3: batch 1; one row per thread). Offset = butterfly-summed prefix
// of pp over j < 2k (64-wide strided walk, pp is L2-hot), plus pp[2k] for
// the odd half.
__global__ __launch_bounds__(256, 4) void finish_kernel(
    const float4* __restrict__ gbuf, const float4* __restrict__ pp,
    const float* __restrict__ bfin, float4* __restrict__ out4) {
  const int tid = threadIdx.x;
  const int bb = tid >> 7;          // batch 0/1
  const int i = tid & 127;          // row within the 128-row group
  const int lane = tid & 63;
  const int aj0 = 2 * blockIdx.x;   // first A-block covered

  // prefix over pp[bb][j] for j < aj0 (each wave does its own walk)
  float4 q = make_float4(0.f, 0.f, 0.f, 0.f);
  for (int j = lane; j < aj0; j += 64) q = f4add(q, pp[bb * NBLK + j]);
#pragma unroll
  for (int off = 32; off > 0; off >>= 1) {
    q.x += __shfl_xor(q.x, off); q.y += __shfl_xor(q.y, off);
    q.z += __shfl_xor(q.z, off); q.w += __shfl_xor(q.w, off);
  }
  if (i >= 64) q = f4add(q, pp[bb * NBLK + aj0]);  // odd A-block adjustment

  const int row = blockIdx.x * 128 + i;
  const float4 v = f4add(gbuf[(size_t)bb * L_TOTAL + row], q);
  const float factor = fp16_roundtrip_pos(1.0f / (float)(row + 1));
  float4 o;
  o.x = fmaf(v.x, factor, bfin[0]);
  o.y = fmaf(v.y, factor, bfin[1]);
  o.z = fmaf(v.z, factor, bfin[2]);
  o.w = fmaf(v.w, factor, bfin[3]);
  out4[(size_t)bb * L_TOTAL + row] = o;
}

extern "C" void kernel_launch(void* const* d_in, const int* in_sizes, int n_in,
                              void* d_out, int out_size, void* d_ws, size_t ws_size,
                              hipStream_t stream) {
  const int* ex = (const int*)d_in[0];            // example [2,128,128,3] int32
  const float4* win4 = (const float4*)d_in[1];    // W_in [1,1024]
  const float4* pos4 = (const float4*)d_in[2];    // pos_enc [49152,1024]
  const float4* wf4 = (const float4*)d_in[3];     // W_final [1024,4]
  const float* bfin = (const float*)d_in[4];      // b_final [4]
  float4* out4 = (float4*)d_out;

  float4* gbuf = (float4*)d_ws;                   // [2][L_TOTAL] float4
  float4* pp = gbuf + (size_t)2 * L_TOTAL;        // [2][NBLK] float4

  gpart_kernel<<<NBLK, 256, 0, stream>>>(ex, win4, pos4, wf4, gbuf, pp);
  finish_kernel<<<NBLK / 2, 256, 0, stream>>>(gbuf, pp, bfin, out4);
}